// Round 2
// baseline (861.880 us; speedup 1.0000x reference)
//
#include <hip/hip_runtime.h>
#include <stdint.h>

#define H_DIM 256
#define NCOL 8192
#define TOPK 512
#define CAND_CAP 8192
#define NBINS 8192  // fkey >> 19

// monotonic float -> uint key (order-preserving for all finite floats)
__device__ __forceinline__ unsigned fkey(float f) {
  unsigned u = __float_as_uint(f);
  unsigned m = (unsigned)((int)u >> 31) | 0x80000000u;
  return u ^ m;
}

__global__ __launch_bounds__(256) void zero_ws(unsigned* __restrict__ ghist,
                                               unsigned* __restrict__ counter) {
  int t = blockIdx.x * blockDim.x + threadIdx.x;
  if (t < NBINS) ghist[t] = 0;
  if (t == 0) *counter = 0;
}

// ---------------- MLP layer: Y[rows,256] = act(X[rows,K] @ W[K,256] + b) ----------------
// block = 32 rows x 128 cols; 256 threads; thread tile = 4 rows x 4 cols.
// X staged in LDS (wave-broadcast reads), W streamed from global (L2) with prefetch.
template <int K, bool RELU>
__global__ __launch_bounds__(256) void mlp_layer(const float* __restrict__ X,
                                                 const float* __restrict__ W,
                                                 const float* __restrict__ bias,
                                                 float* __restrict__ Y) {
  __shared__ float Xs[32 * K];  // K=128: 16KB, K=256: 32KB
  const int t = threadIdx.x;
  const int tx = t & 31;        // col group: cols c0 + tx*4 .. +3
  const int ty = t >> 5;        // row group: rows row0 + ty*4 .. +3
  const int row0 = blockIdx.x * 32;
  const int c0 = blockIdx.y * 128;
  const int wcol = c0 + tx * 4;

  for (int f = t; f < 8 * K; f += 256) {  // 32*K/4 float4s
    *(float4*)(Xs + f * 4) = *(const float4*)(X + row0 * K + f * 4);
  }
  __syncthreads();

  float acc[4][4];
#pragma unroll
  for (int r = 0; r < 4; r++)
#pragma unroll
    for (int c = 0; c < 4; c++) acc[r][c] = 0.f;

  float4 w[4], wn[4];
#pragma unroll
  for (int j = 0; j < 4; j++) w[j] = *(const float4*)(W + j * H_DIM + wcol);

  for (int d = 0; d < K; d += 4) {
    const int dn = (d + 4 < K) ? d + 4 : d;
#pragma unroll
    for (int j = 0; j < 4; j++) wn[j] = *(const float4*)(W + (dn + j) * H_DIM + wcol);
    float4 x4[4];
#pragma unroll
    for (int r = 0; r < 4; r++) x4[r] = *(const float4*)(Xs + (ty * 4 + r) * K + d);
#pragma unroll
    for (int r = 0; r < 4; r++) {
      const float xv[4] = {x4[r].x, x4[r].y, x4[r].z, x4[r].w};
#pragma unroll
      for (int j = 0; j < 4; j++) {
        acc[r][0] = fmaf(xv[j], w[j].x, acc[r][0]);
        acc[r][1] = fmaf(xv[j], w[j].y, acc[r][1]);
        acc[r][2] = fmaf(xv[j], w[j].z, acc[r][2]);
        acc[r][3] = fmaf(xv[j], w[j].w, acc[r][3]);
      }
    }
#pragma unroll
    for (int j = 0; j < 4; j++) w[j] = wn[j];
  }

  const float4 bv = *(const float4*)(bias + wcol);
#pragma unroll
  for (int r = 0; r < 4; r++) {
    float4 v;
    v.x = acc[r][0] + bv.x;
    v.y = acc[r][1] + bv.y;
    v.z = acc[r][2] + bv.z;
    v.w = acc[r][3] + bv.w;
    if (RELU) {
      v.x = fmaxf(v.x, 0.f);
      v.y = fmaxf(v.y, 0.f);
      v.z = fmaxf(v.z, 0.f);
      v.w = fmaxf(v.w, 0.f);
    }
    *(float4*)(Y + (row0 + ty * 4 + r) * H_DIM + wcol) = v;
  }
}

// ---------------- big GEMM: C[8192,8192] = A[8192,256] * B[8192,256]^T ----------------
// block tile 128(M) x 256(N), 256 threads, 8x16 per thread, K chunks of 32.
// LDS strides padded (132/260) -> staging write conflicts 8-way -> 4-way.
#define AS_LD 132
#define BS_LD 260
__global__ __launch_bounds__(256, 3) void gemm_sim(const float* __restrict__ A,
                                                   const float* __restrict__ B,
                                                   float* __restrict__ C) {
  __shared__ float As[32 * AS_LD];  // 16.5KB  [k][row]
  __shared__ float Bs[32 * BS_LD];  // 32.5KB  [k][col]
  const int t = threadIdx.x;
  const int tx = t & 15, ty = t >> 4;
  const int m0 = blockIdx.y * 128, n0 = blockIdx.x * 256;
  float acc[8][16];
#pragma unroll
  for (int i = 0; i < 8; i++)
#pragma unroll
    for (int j = 0; j < 16; j++) acc[i][j] = 0.f;

  for (int kc = 0; kc < H_DIM; kc += 32) {
    __syncthreads();
#pragma unroll
    for (int i = 0; i < 4; i++) {
      int v = t + i * 256;
      int r = v >> 3, k4 = v & 7;
      float4 a4 = *(const float4*)(A + (m0 + r) * H_DIM + kc + k4 * 4);
      As[(k4 * 4 + 0) * AS_LD + r] = a4.x;
      As[(k4 * 4 + 1) * AS_LD + r] = a4.y;
      As[(k4 * 4 + 2) * AS_LD + r] = a4.z;
      As[(k4 * 4 + 3) * AS_LD + r] = a4.w;
    }
#pragma unroll
    for (int i = 0; i < 8; i++) {
      int v = t + i * 256;
      int r = v >> 3, k4 = v & 7;
      float4 b4 = *(const float4*)(B + (n0 + r) * H_DIM + kc + k4 * 4);
      Bs[(k4 * 4 + 0) * BS_LD + r] = b4.x;
      Bs[(k4 * 4 + 1) * BS_LD + r] = b4.y;
      Bs[(k4 * 4 + 2) * BS_LD + r] = b4.z;
      Bs[(k4 * 4 + 3) * BS_LD + r] = b4.w;
    }
    __syncthreads();
#pragma unroll 2
    for (int kk = 0; kk < 32; kk++) {
      float a[8], b[16];
      *(float4*)&a[0] = *(const float4*)(As + kk * AS_LD + ty * 8);
      *(float4*)&a[4] = *(const float4*)(As + kk * AS_LD + ty * 8 + 4);
#pragma unroll
      for (int m = 0; m < 4; m++)
        *(float4*)&b[m * 4] = *(const float4*)(Bs + kk * BS_LD + tx * 4 + m * 64);
#pragma unroll
      for (int i = 0; i < 8; i++)
#pragma unroll
        for (int j = 0; j < 16; j++) acc[i][j] = fmaf(a[i], b[j], acc[i][j]);
    }
  }
#pragma unroll
  for (int i = 0; i < 8; i++) {
    size_t row = (size_t)(m0 + ty * 8 + i);
#pragma unroll
    for (int m = 0; m < 4; m++) {
      float4 v;
      v.x = acc[i][m * 4 + 0];
      v.y = acc[i][m * 4 + 1];
      v.z = acc[i][m * 4 + 2];
      v.w = acc[i][m * 4 + 3];
      *(float4*)(C + row * NCOL + n0 + tx * 4 + m * 64) = v;
    }
  }
}

// ---------------- histogram pass over sim (8192 bins, per-block LDS) ----------------
__global__ __launch_bounds__(256) void hist_pass(const float* __restrict__ sim,
                                                 unsigned* __restrict__ ghist) {
  __shared__ unsigned hist[NBINS];  // 32KB
  const int t = threadIdx.x;
  for (int i = t; i < NBINS; i += 256) hist[i] = 0;
  __syncthreads();
  const int stride = gridDim.x * blockDim.x;
  const int total4 = (NCOL * NCOL) / 4;
  const float4* s4 = (const float4*)sim;
  for (int i = blockIdx.x * blockDim.x + t; i < total4; i += stride) {
    float4 v = s4[i];
    atomicAdd(&hist[fkey(v.x) >> 19], 1u);
    atomicAdd(&hist[fkey(v.y) >> 19], 1u);
    atomicAdd(&hist[fkey(v.z) >> 19], 1u);
    atomicAdd(&hist[fkey(v.w) >> 19], 1u);
  }
  __syncthreads();
  for (int b = t; b < NBINS; b += 256) {
    unsigned c = hist[b];
    if (c) atomicAdd(&ghist[b], c);
  }
}

// ---------------- threshold: smallest bin b* s.t. count(key >= b*<<19) >= TOPK ----------------
__global__ __launch_bounds__(256) void find_thresh(const unsigned* __restrict__ ghist,
                                                   unsigned* __restrict__ thresh) {
  __shared__ unsigned part[256];
  const int t = threadIdx.x;
  unsigned s = 0;
#pragma unroll
  for (int b = 0; b < 32; b++) s += ghist[t * 32 + b];
  part[t] = s;
  __syncthreads();
  if (t == 0) {
    unsigned cum = 0;
    int g = 255;
    for (; g > 0; g--) {
      if (cum + part[g] >= TOPK) break;
      cum += part[g];
    }
    int bsel = g * 32;
    for (int b = g * 32 + 31; b >= g * 32; b--) {
      cum += ghist[b];
      if (cum >= TOPK) { bsel = b; break; }
    }
    *thresh = (unsigned)bsel << 19;
  }
}

// ---------------- collect all candidates >= threshold ----------------
__global__ __launch_bounds__(256) void collect(const float* __restrict__ sim,
                                               const unsigned* __restrict__ thresh,
                                               unsigned long long* __restrict__ cand,
                                               unsigned* __restrict__ counter) {
  const unsigned thr = *thresh;
  const int stride = gridDim.x * blockDim.x;
  const int total4 = (NCOL * NCOL) / 4;
  const float4* s4 = (const float4*)sim;
  for (int i = blockIdx.x * blockDim.x + threadIdx.x; i < total4; i += stride) {
    float4 v = s4[i];
    unsigned base = (unsigned)i * 4u;
    unsigned k;
    k = fkey(v.x);
    if (k >= thr) {
      unsigned p = atomicAdd(counter, 1u);
      if (p < CAND_CAP) cand[p] = ((unsigned long long)k << 32) | (unsigned long long)(0xFFFFFFFFu - (base + 0u));
    }
    k = fkey(v.y);
    if (k >= thr) {
      unsigned p = atomicAdd(counter, 1u);
      if (p < CAND_CAP) cand[p] = ((unsigned long long)k << 32) | (unsigned long long)(0xFFFFFFFFu - (base + 1u));
    }
    k = fkey(v.z);
    if (k >= thr) {
      unsigned p = atomicAdd(counter, 1u);
      if (p < CAND_CAP) cand[p] = ((unsigned long long)k << 32) | (unsigned long long)(0xFFFFFFFFu - (base + 2u));
    }
    k = fkey(v.w);
    if (k >= thr) {
      unsigned p = atomicAdd(counter, 1u);
      if (p < CAND_CAP) cand[p] = ((unsigned long long)k << 32) | (unsigned long long)(0xFFFFFFFFu - (base + 3u));
    }
  }
}

// ---------------- single-block bitonic sort of candidates, write top-512 (row,col) ----------------
__global__ __launch_bounds__(1024) void sort_topk(const unsigned long long* __restrict__ cand,
                                                  const unsigned* __restrict__ counter,
                                                  float* __restrict__ out) {
  __shared__ unsigned long long s[CAND_CAP];  // 64KB
  const int t = threadIdx.x;
  int n = (int)min(*counter, (unsigned)CAND_CAP);
  int P = 512;
  while (P < n) P <<= 1;
  for (int i = t; i < P; i += 1024) s[i] = (i < n) ? cand[i] : 0ULL;
  __syncthreads();
  for (int k = 2; k <= P; k <<= 1) {
    for (int j = k >> 1; j > 0; j >>= 1) {
      for (int i = t; i < P; i += 1024) {
        int l = i ^ j;
        if (l > i) {
          bool desc = ((i & k) == 0);
          unsigned long long a = s[i], b = s[l];
          bool sw = desc ? (a < b) : (a > b);
          if (sw) { s[i] = b; s[l] = a; }
        }
      }
      __syncthreads();
    }
  }
  if (t < TOPK) {
    unsigned long long c = s[t];
    unsigned idx = 0xFFFFFFFFu - (unsigned)(c & 0xFFFFFFFFull);
    unsigned row = idx >> 13;
    unsigned col = idx & 8191u;
    out[t * 2 + 0] = (float)row;
    out[t * 2 + 1] = (float)col;
  }
}

extern "C" void kernel_launch(void* const* d_in, const int* in_sizes, int n_in,
                              void* d_out, int out_size, void* d_ws, size_t ws_size,
                              hipStream_t stream) {
  const float* desc0 = (const float*)d_in[0];
  const float* desc1 = (const float*)d_in[1];
  const float* W0a = (const float*)d_in[2];
  const float* b0a = (const float*)d_in[3];
  const float* W0b = (const float*)d_in[4];
  const float* b0b = (const float*)d_in[5];
  const float* W1a = (const float*)d_in[6];
  const float* b1a = (const float*)d_in[7];
  const float* W1b = (const float*)d_in[8];
  const float* b1b = (const float*)d_in[9];

  char* ws = (char*)d_ws;
  unsigned* ghist = (unsigned*)ws;                               // 32KB
  unsigned* counter = (unsigned*)(ws + 32768);                   // 4B
  unsigned* thresh = (unsigned*)(ws + 32772);                    // 4B
  unsigned long long* cand = (unsigned long long*)(ws + 32832);  // 64KB
  float* mdesc0 = (float*)(ws + 131072);                         // 8MB
  float* mdesc1 = mdesc0 + 8192 * 256;                           // 8MB
  float* hbuf = mdesc1 + 8192 * 256;                             // 8MB

  float* outf = (float*)d_out;
  float* sim = outf + TOPK * 2;  // sim at float offset 1024 (16B aligned)

  zero_ws<<<32, 256, 0, stream>>>(ghist, counter);

  mlp_layer<128, true><<<dim3(256, 2), 256, 0, stream>>>(desc0, W0a, b0a, hbuf);
  mlp_layer<256, false><<<dim3(256, 2), 256, 0, stream>>>(hbuf, W0b, b0b, mdesc0);
  mlp_layer<128, true><<<dim3(256, 2), 256, 0, stream>>>(desc1, W1a, b1a, hbuf);
  mlp_layer<256, false><<<dim3(256, 2), 256, 0, stream>>>(hbuf, W1b, b1b, mdesc1);

  gemm_sim<<<dim3(32, 64), 256, 0, stream>>>(mdesc0, mdesc1, sim);
  hist_pass<<<2048, 256, 0, stream>>>(sim, ghist);
  find_thresh<<<1, 256, 0, stream>>>(ghist, thresh);
  collect<<<4096, 256, 0, stream>>>(sim, thresh, cand, counter);
  sort_topk<<<1, 1024, 0, stream>>>(cand, counter, outf);
}